// Round 7
// baseline (124.268 us; speedup 1.0000x reference)
//
#include <hip/hip_runtime.h>

typedef __attribute__((ext_vector_type(8))) short bf16x8;   // 8 bf16 (4 VGPRs)
typedef __attribute__((ext_vector_type(4))) float f32x4;

#define BM 128
#define BN 128
#define BKA 32      // K-step (A fp32 chunk = 128 B/row; B bf16 chunk = 64 B/row)
#define NKT 8       // 256 / BKA

__device__ inline unsigned short f2bf(float f) {
  unsigned int u = __builtin_bit_cast(unsigned int, f);
  u += 0x7fffu + ((u >> 16) & 1u);     // round-to-nearest-even
  return (unsigned short)(u >> 16);
}

__device__ inline void gload16(const void* g, void* l) {
  __builtin_amdgcn_global_load_lds(
      (const __attribute__((address_space(1))) void*)g,
      (__attribute__((address_space(3))) void*)l, 16, 0, 0);
}

// C is tiny (512x256): bf16 copy pre-XOR-swizzled within each 64B sub-block
// (byte ^= (row&3)<<4) + exact fp32 csq. One wave per row.
__global__ void prep_c(const float* __restrict__ C, unsigned short* __restrict__ Cbf,
                       float* __restrict__ csq, int K) {
  const int w = threadIdx.x >> 6, lane = threadIdx.x & 63;
  const int row = blockIdx.x * 4 + w;
  if (row >= K) return;
  const float4 v = *reinterpret_cast<const float4*>(&C[(size_t)row * 256 + lane * 4]);
  ushort4 b;
  b.x = f2bf(v.x); b.y = f2bf(v.y); b.z = f2bf(v.z); b.w = f2bf(v.w);
  const int boff = (lane * 8) ^ ((row & 3) << 4);   // permutation within 64B chunks
  *reinterpret_cast<ushort4*>((char*)Cbf + (size_t)row * 512 + boff) = b;
  float sq = v.x * v.x + v.y * v.y + v.z * v.z + v.w * v.w;
#pragma unroll
  for (int o = 32; o; o >>= 1) sq += __shfl_xor(sq, o);
  if (lane == 0) csq[row] = sq;
}

// Fused: out[m][n] = ||F_m||^2 + ||C_n||^2 - 2*F_m.C_n
// A staged RAW FP32 via global_load_lds with SOURCE-ADDRESS swizzle (m173:
// F is unswizzled, LDS dest linear, read-side XOR matches). bf16 cvt + exact
// row norms in the compute phase. B from pre-swizzled bf16. Double-buffered,
// counted vmcnt(6). Swapped MFMA operands -> float4 epilogue stores.
// 128x128 tile, BK=32 (8 K-iters), 4 waves (2x2), 3 blocks/CU (48KB LDS).
__global__ __launch_bounds__(256, 3) void dist_fused(
    const float* __restrict__ F, const unsigned short* __restrict__ Cbf,
    const float* __restrict__ csq, float* __restrict__ out, int M, int N) {
  __shared__ __align__(16) char As[2][BM * 128];   // fp32: 2 x 16 KB, [row][128B]
  __shared__ __align__(16) char Bs[2][BN * 64];    // bf16: 2 x  8 KB, [row][64B]

  const int t = threadIdx.x;
  const int w = t >> 6, lane = t & 63;
  const int wr = w >> 1, wc = w & 1;          // wave -> 64x64 quadrant
  const int rl = lane & 15, kh = lane >> 4;   // fragment lane decomposition
  const int amaskA = (rl & 7) << 4;           // A read-side XOR (row&7 == rl&7)
  const int amaskB = (rl & 3) << 4;           // B read-side XOR (row&3 == rl&3)

  // Bijective XCD swizzle (1024 blocks, %8==0); n-tile fastest so the 4
  // blocks sharing an F m-panel run concurrently on the same XCD (L2-hot).
  const int nwg = gridDim.x;
  const int cpx = nwg >> 3;
  const int work = (blockIdx.x & 7) * cpx + (blockIdx.x >> 3);
  const int ntiles = N / BN;                  // 4
  const int n0 = (work % ntiles) * BN;
  const int m0 = (work / ntiles) * BM;

  // Staging decompositions (thread-constant).
  // A: 4 rounds x 32 rows x 128B; source col XOR-swizzled (F raw in memory).
  const int a_row = t >> 3;                                   // 0..31
  const int a_cb = ((t & 7) * 16) ^ ((a_row & 7) << 4);       // swizzled col in 128B chunk
  const char* Asrc = (const char*)F + (size_t)(m0 + a_row) * 1024 + a_cb;
  // A j-round advance: 32 rows * 1024 B = 32768 B; kt advance: 128 B.
  // B: 2 rounds x 64 rows x 64B; memory already swizzled within 64B chunks.
  const int b_row = t >> 2;                                   // 0..63
  const int b_cb = (t & 3) * 16;                              // linear col in 64B chunk
  const char* Bsrc = (const char*)Cbf + (size_t)(n0 + b_row) * 512 + b_cb;
  // B j-round advance: 64 rows * 512 B = 32768 B; kt advance: 64 B.

#define STAGE(KT, BUF)                                                        \
  {                                                                           \
    _Pragma("unroll")                                                         \
    for (int j = 0; j < 4; ++j)                                               \
      gload16(Asrc + (size_t)j * 32768 + (KT) * 128,                          \
              (char*)As[BUF] + j * 4096 + w * 1024);                          \
    _Pragma("unroll")                                                         \
    for (int j = 0; j < 2; ++j)                                               \
      gload16(Bsrc + (size_t)j * 32768 + (KT) * 64,                           \
              (char*)Bs[BUF] + j * 4096 + w * 1024);                          \
  }

  // prologue: stage kt=0 into buffer 0 (6 loads in flight)
  STAGE(0, 0)

  // csq prefetch: with swapped operands, lane needs 4 CONSECUTIVE centers.
  float4 cs4[4];
#pragma unroll
  for (int ni = 0; ni < 4; ni++)
    cs4[ni] = *reinterpret_cast<const float4*>(&csq[n0 + wc * 64 + ni * 16 + kh * 4]);

  f32x4 acc[4][4];
#pragma unroll
  for (int i = 0; i < 4; i++)
#pragma unroll
    for (int j = 0; j < 4; j++) acc[i][j] = (f32x4){0.f, 0.f, 0.f, 0.f};
  float rsq[4] = {0.f, 0.f, 0.f, 0.f};

#pragma unroll
  for (int kt = 0; kt < NKT; ++kt) {
    const int cur = kt & 1;
    if (kt < NKT - 1) {
      STAGE(kt + 1, cur ^ 1)
      asm volatile("s_waitcnt vmcnt(6)" ::: "memory");   // tile kt landed; next 6 in flight
    } else {
      asm volatile("s_waitcnt vmcnt(0)" ::: "memory");
    }
    __builtin_amdgcn_s_barrier();
    asm volatile("" ::: "memory");

    // B fragments (bf16, read-side unswizzle within 64B rows)
    bf16x8 bfr[4];
#pragma unroll
    for (int ni = 0; ni < 4; ni++)
      bfr[ni] = *reinterpret_cast<const bf16x8*>(
          (const char*)Bs[cur] + (wc * 64 + ni * 16 + rl) * 64 + ((kh * 16) ^ amaskB));

#pragma unroll
    for (int mi = 0; mi < 4; mi++) {
      const char* arow = (const char*)As[cur] + (wr * 64 + mi * 16 + rl) * 128;
      const f32x4 a0 = *reinterpret_cast<const f32x4*>(arow + ((kh * 32) ^ amaskA));
      const f32x4 a1 = *reinterpret_cast<const f32x4*>(arow + ((kh * 32 + 16) ^ amaskA));
      rsq[mi] += a0[0] * a0[0] + a0[1] * a0[1] + a0[2] * a0[2] + a0[3] * a0[3] +
                 a1[0] * a1[0] + a1[1] * a1[1] + a1[2] * a1[2] + a1[3] * a1[3];
      bf16x8 af;
      af[0] = (short)f2bf(a0[0]); af[1] = (short)f2bf(a0[1]);
      af[2] = (short)f2bf(a0[2]); af[3] = (short)f2bf(a0[3]);
      af[4] = (short)f2bf(a1[0]); af[5] = (short)f2bf(a1[1]);
      af[6] = (short)f2bf(a1[2]); af[7] = (short)f2bf(a1[3]);
      // SWAPPED operands: D row-dim = bfr's row index (center), col = af's (F-row).
#pragma unroll
      for (int ni = 0; ni < 4; ni++)
        acc[mi][ni] = __builtin_amdgcn_mfma_f32_16x16x32_bf16(
            bfr[ni], af, acc[mi][ni], 0, 0, 0);
    }
    __builtin_amdgcn_s_barrier();    // all waves done with buf[cur] before restage
    asm volatile("" ::: "memory");
  }

  // Row norms: lane's rsq[mi] is the kh-slice partial for F-row mi*16+rl.
  // shfl_xor(16,32) sums the 4 kh groups -> EVERY lane holds its row's full sum.
  float fv[4];
#pragma unroll
  for (int mi = 0; mi < 4; mi++) {
    float v = rsq[mi];
    v += __shfl_xor(v, 16);
    v += __shfl_xor(v, 32);
    fv[mi] = v;   // = ||F_{m0+wr*64+mi*16+rl}||^2
  }

  // Epilogue (swapped layout): lane (rl,kh), reg r ->
  //   m = m0+wr*64+mi*16+rl  (lane-held fv[mi]),  n = n0+wc*64+ni*16+kh*4+r
  // 4 consecutive n per lane -> float4 stores.
#pragma unroll
  for (int mi = 0; mi < 4; mi++) {
    const int m = m0 + wr * 64 + mi * 16 + rl;
#pragma unroll
    for (int ni = 0; ni < 4; ni++) {
      const int n = n0 + wc * 64 + ni * 16 + kh * 4;
      float4 v;
      v.x = fv[mi] + cs4[ni].x - 2.0f * acc[mi][ni][0];
      v.y = fv[mi] + cs4[ni].y - 2.0f * acc[mi][ni][1];
      v.z = fv[mi] + cs4[ni].z - 2.0f * acc[mi][ni][2];
      v.w = fv[mi] + cs4[ni].w - 2.0f * acc[mi][ni][3];
      *reinterpret_cast<float4*>(&out[(size_t)m * N + n]) = v;
    }
  }
}

extern "C" void kernel_launch(void* const* d_in, const int* in_sizes, int n_in,
                              void* d_out, int out_size, void* d_ws, size_t ws_size,
                              hipStream_t stream) {
  const float* F = (const float*)d_in[0];   // (16, 2048, 256) fp32
  const float* C = (const float*)d_in[1];   // (1, 512, 256) fp32
  float* out = (float*)d_out;               // (16, 2048, 512) fp32
  const int D = 256;
  const int M = in_sizes[0] / D;            // 32768
  const int N = in_sizes[1] / D;            // 512

  unsigned short* Cbf = (unsigned short*)d_ws;    // N*256 bf16 (64B-block swizzled)
  float* csq = (float*)(Cbf + (size_t)N * D);     // N fp32

  hipLaunchKernelGGL(prep_c, dim3(N / 4), dim3(256), 0, stream, C, Cbf, csq, N);
  const int nwg = (M / BM) * (N / BN);            // 1024, divisible by 8
  hipLaunchKernelGGL(dist_fused, dim3(nwg), dim3(256), 0, stream,
                     F, Cbf, csq, out, M, N);
}

// Round 8
// 47.159 us; speedup vs baseline: 2.6351x; 2.6351x over previous
//
#include <hip/hip_runtime.h>

typedef __attribute__((ext_vector_type(8))) short bf16x8;   // 8 bf16 (4 VGPRs)
typedef __attribute__((ext_vector_type(4))) float f32x4;

#define BM 64       // F-rows per block
#define BN 512      // ALL centers per block -> F read exactly once, no L2 reuse needed
#define NKT 8       // 256 / 32 K-steps

__device__ inline unsigned short f2bf(float f) {
  unsigned int u = __builtin_bit_cast(unsigned int, f);
  u += 0x7fffu + ((u >> 16) & 1u);     // round-to-nearest-even
  return (unsigned short)(u >> 16);
}

__device__ inline void gload16(const void* g, void* l) {
  __builtin_amdgcn_global_load_lds(
      (const __attribute__((address_space(1))) void*)g,
      (__attribute__((address_space(3))) void*)l, 16, 0, 0);
}

// C is tiny (512x256): bf16 copy pre-XOR-swizzled within each 64B sub-block
// (byte ^= (row&3)<<4) + exact fp32 csq. One wave per row. [verified r7]
__global__ void prep_c(const float* __restrict__ C, unsigned short* __restrict__ Cbf,
                       float* __restrict__ csq, int K) {
  const int w = threadIdx.x >> 6, lane = threadIdx.x & 63;
  const int row = blockIdx.x * 4 + w;
  if (row >= K) return;
  const float4 v = *reinterpret_cast<const float4*>(&C[(size_t)row * 256 + lane * 4]);
  ushort4 b;
  b.x = f2bf(v.x); b.y = f2bf(v.y); b.z = f2bf(v.z); b.w = f2bf(v.w);
  const int boff = (lane * 8) ^ ((row & 3) << 4);   // permutation within 64B chunks
  *reinterpret_cast<ushort4*>((char*)Cbf + (size_t)row * 512 + boff) = b;
  float sq = v.x * v.x + v.y * v.y + v.z * v.z + v.w * v.w;
#pragma unroll
  for (int o = 32; o; o >>= 1) sq += __shfl_xor(sq, o);
  if (lane == 0) csq[row] = sq;
}

// Fused: out[m][n] = ||F_m||^2 + ||C_n||^2 - 2*F_m.C_n
// Block = 64 F-rows x ALL 512 centers. A staged RAW FP32 via global_load_lds
// (source-address swizzle, m173); bf16 cvt + exact row norms in compute
// phase. B from pre-swizzled bf16 Cbf. Double-buffered, counted vmcnt(10).
// 4 waves 2x2 (32m x 256n each), swapped MFMA -> float4 stores. 2 blocks/CU.
__global__ __launch_bounds__(256, 2) void dist_fused(
    const float* __restrict__ F, const unsigned short* __restrict__ Cbf,
    const float* __restrict__ csq, float* __restrict__ out, int M, int N) {
  __shared__ __align__(16) char As[2][BM * 128];   // fp32: 2 x 8 KB, [row][128B]
  __shared__ __align__(16) char Bs[2][BN * 64];    // bf16: 2 x 32 KB, [row][64B]

  const int t = threadIdx.x;
  const int w = t >> 6, lane = t & 63;
  const int wr = w >> 1, wc = w & 1;          // wave -> 32m x 256n quadrant
  const int rl = lane & 15, kh = lane >> 4;   // fragment lane decomposition
  const int amaskA = (rl & 7) << 4;           // A read-side XOR (row&7 == rl&7)
  const int amaskB = (rl & 3) << 4;           // B read-side XOR (row&3 == rl&3)

  const int m0 = blockIdx.x * BM;

  // Staging decompositions (thread-constant).
  // A: 2 rounds x 32 rows x 128B; source col XOR-swizzled (F raw in memory).
  const int a_row = t >> 3;                                   // 0..31
  const int a_cb = ((t & 7) * 16) ^ ((a_row & 7) << 4);       // swizzled col in 128B chunk
  const char* Asrc = (const char*)F + (size_t)(m0 + a_row) * 1024 + a_cb;
  // A j-round advance: 32 rows * 1024 B = 32768 B; kt advance: 128 B.
  // B: 8 rounds x 64 rows x 64B; memory already swizzled within 64B chunks.
  const int b_row = t >> 2;                                   // 0..63
  const int b_cb = (t & 3) * 16;                              // linear col in 64B chunk
  const char* Bsrc = (const char*)Cbf + (size_t)b_row * 512 + b_cb;
  // B j-round advance: 64 rows * 512 B = 32768 B; kt advance: 64 B.

#define STAGE(KT, BUF)                                                        \
  {                                                                           \
    _Pragma("unroll")                                                         \
    for (int j = 0; j < 2; ++j)                                               \
      gload16(Asrc + (size_t)j * 32768 + (KT) * 128,                          \
              (char*)As[BUF] + j * 4096 + w * 1024);                          \
    _Pragma("unroll")                                                         \
    for (int j = 0; j < 8; ++j)                                               \
      gload16(Bsrc + (size_t)j * 32768 + (KT) * 64,                           \
              (char*)Bs[BUF] + j * 4096 + w * 1024);                          \
  }

  // prologue: stage kt=0 into buffer 0 (10 loads in flight)
  STAGE(0, 0)

  f32x4 acc[2][16];
#pragma unroll
  for (int i = 0; i < 2; i++)
#pragma unroll
    for (int j = 0; j < 16; j++) acc[i][j] = (f32x4){0.f, 0.f, 0.f, 0.f};
  float rsq[2] = {0.f, 0.f};

#pragma unroll
  for (int kt = 0; kt < NKT; ++kt) {
    const int cur = kt & 1;
    if (kt < NKT - 1) {
      STAGE(kt + 1, cur ^ 1)
      asm volatile("s_waitcnt vmcnt(10)" ::: "memory");  // tile kt landed; next 10 in flight
    } else {
      asm volatile("s_waitcnt vmcnt(0)" ::: "memory");
    }
    __builtin_amdgcn_s_barrier();
    asm volatile("" ::: "memory");

    // A fragments: fp32 -> bf16 cvt + exact square accumulation (VALU idle here)
    bf16x8 af[2];
#pragma unroll
    for (int mi = 0; mi < 2; mi++) {
      const char* arow = (const char*)As[cur] + (wr * 32 + mi * 16 + rl) * 128;
      const f32x4 a0 = *reinterpret_cast<const f32x4*>(arow + ((kh * 32) ^ amaskA));
      const f32x4 a1 = *reinterpret_cast<const f32x4*>(arow + ((kh * 32 + 16) ^ amaskA));
      rsq[mi] += a0[0] * a0[0] + a0[1] * a0[1] + a0[2] * a0[2] + a0[3] * a0[3] +
                 a1[0] * a1[0] + a1[1] * a1[1] + a1[2] * a1[2] + a1[3] * a1[3];
      bf16x8 v;
      v[0] = (short)f2bf(a0[0]); v[1] = (short)f2bf(a0[1]);
      v[2] = (short)f2bf(a0[2]); v[3] = (short)f2bf(a0[3]);
      v[4] = (short)f2bf(a1[0]); v[5] = (short)f2bf(a1[1]);
      v[6] = (short)f2bf(a1[2]); v[7] = (short)f2bf(a1[3]);
      af[mi] = v;
    }

#pragma unroll
    for (int ni = 0; ni < 16; ni++) {
      const bf16x8 bfr = *reinterpret_cast<const bf16x8*>(
          (const char*)Bs[cur] + (wc * 256 + ni * 16 + rl) * 64 + ((kh * 16) ^ amaskB));
      // SWAPPED operands: D row-dim = center index, col = F-row. [verified r7]
#pragma unroll
      for (int mi = 0; mi < 2; mi++)
        acc[mi][ni] = __builtin_amdgcn_mfma_f32_16x16x32_bf16(
            bfr, af[mi], acc[mi][ni], 0, 0, 0);
    }
    __builtin_amdgcn_s_barrier();    // all waves done with buf[cur] before restage
    asm volatile("" ::: "memory");
  }

  // Row norms: rsq[mi] is the kh-slice partial for F-row mi*16+rl.
  // shfl_xor(16,32) sums the 4 kh groups -> every lane holds its row's sum.
  float fv[2];
#pragma unroll
  for (int mi = 0; mi < 2; mi++) {
    float v = rsq[mi];
    v += __shfl_xor(v, 16);
    v += __shfl_xor(v, 32);
    fv[mi] = v;   // = ||F_{m0+wr*32+mi*16+rl}||^2
  }

  // Epilogue (swapped layout): lane (rl,kh), reg r ->
  //   m = m0+wr*32+mi*16+rl,  n = wc*256+ni*16+kh*4+r  -> float4 stores.
  // csq read per-ni from global (2 KB, L2-resident).
#pragma unroll
  for (int ni = 0; ni < 16; ni++) {
    const int n = wc * 256 + ni * 16 + kh * 4;
    const float4 cs4 = *reinterpret_cast<const float4*>(&csq[n]);
#pragma unroll
    for (int mi = 0; mi < 2; mi++) {
      const int m = m0 + wr * 32 + mi * 16 + rl;
      float4 v;
      v.x = fv[mi] + cs4.x - 2.0f * acc[mi][ni][0];
      v.y = fv[mi] + cs4.y - 2.0f * acc[mi][ni][1];
      v.z = fv[mi] + cs4.z - 2.0f * acc[mi][ni][2];
      v.w = fv[mi] + cs4.w - 2.0f * acc[mi][ni][3];
      *reinterpret_cast<float4*>(&out[(size_t)m * N + n]) = v;
    }
  }
}

extern "C" void kernel_launch(void* const* d_in, const int* in_sizes, int n_in,
                              void* d_out, int out_size, void* d_ws, size_t ws_size,
                              hipStream_t stream) {
  const float* F = (const float*)d_in[0];   // (16, 2048, 256) fp32
  const float* C = (const float*)d_in[1];   // (1, 512, 256) fp32
  float* out = (float*)d_out;               // (16, 2048, 512) fp32
  const int D = 256;
  const int M = in_sizes[0] / D;            // 32768
  const int N = in_sizes[1] / D;            // 512

  unsigned short* Cbf = (unsigned short*)d_ws;    // N*256 bf16 (64B-block swizzled)
  float* csq = (float*)(Cbf + (size_t)N * D);     // N fp32

  hipLaunchKernelGGL(prep_c, dim3(N / 4), dim3(256), 0, stream, C, Cbf, csq, N);
  hipLaunchKernelGGL(dist_fused, dim3(M / BM), dim3(256), 0, stream,
                     F, Cbf, csq, out, M, N);
}

// Round 9
// 34.576 us; speedup vs baseline: 3.5940x; 1.3639x over previous
//
#include <hip/hip_runtime.h>

typedef __attribute__((ext_vector_type(8))) short bf16x8;   // 8 bf16 (4 VGPRs)
typedef __attribute__((ext_vector_type(4))) float f32x4;

#define NCH 8       // n-chunks of 64 centers

__device__ inline unsigned short f2bf(float f) {
  unsigned int u = __builtin_bit_cast(unsigned int, f);
  u += 0x7fffu + ((u >> 16) & 1u);     // round-to-nearest-even
  return (unsigned short)(u >> 16);
}

__device__ inline void gload16(const void* g, void* l) {
  __builtin_amdgcn_global_load_lds(
      (const __attribute__((address_space(1))) void*)g,
      (__attribute__((address_space(3))) void*)l, 16, 0, 0);
}

// C (512x256): bf16 copy pre-XOR-swizzled within each 128B sub-block of the
// 512B row (byte ^= (row&7)<<4) + exact fp32 csq. One wave per row.
__global__ void prep_c(const float* __restrict__ C, unsigned short* __restrict__ Cbf,
                       float* __restrict__ csq, int K) {
  const int w = threadIdx.x >> 6, lane = threadIdx.x & 63;
  const int row = blockIdx.x * 4 + w;
  if (row >= K) return;
  const float4 v = *reinterpret_cast<const float4*>(&C[(size_t)row * 256 + lane * 4]);
  ushort4 b;
  b.x = f2bf(v.x); b.y = f2bf(v.y); b.z = f2bf(v.z); b.w = f2bf(v.w);
  const int boff = (lane * 8) ^ ((row & 7) << 4);
  *reinterpret_cast<ushort4*>((char*)Cbf + (size_t)row * 512 + boff) = b;
  float sq = v.x * v.x + v.y * v.y + v.z * v.z + v.w * v.w;
#pragma unroll
  for (int o = 32; o; o >>= 1) sq += __shfl_xor(sq, o);
  if (lane == 0) csq[row] = sq;
}

// Fused: out[m][n] = ||F_m||^2 + ||C_n||^2 - 2*F_m.C_n
// Wave owns 16 F-rows: A loaded DIRECTLY to registers from F (16 deep
// independent HBM loads/lane, no LDS, no barrier on the F path), cvt to
// bf16 frags + exact row norm once. B (L2-hot Cbf) via LDS in n-chunks of
// 64 x fullK (32KB), double-buffered, counted vmcnt(8). Output emitted per
// chunk (acc = 16 VGPRs). Swapped MFMA -> float4 stores. 2 blocks/CU.
__global__ __launch_bounds__(256, 2) void dist_fused(
    const float* __restrict__ F, const unsigned short* __restrict__ Cbf,
    const float* __restrict__ csq, float* __restrict__ out, int M, int N) {
  __shared__ __align__(16) char Bs[2][64 * 512];   // 2 x 32 KB, [row][512B bf16 K-major]

  const int t = threadIdx.x;
  const int w = t >> 6, l = t & 63;
  const int rl = l & 15, kh = l >> 4;
  const int amask = (rl & 7) << 4;    // B read-side XOR (Bs row % 8 == rl % 8)
  const int m0 = blockIdx.x * 64;

  // B staging (thread-constant): 8 rounds x 8 rows x 512B per chunk.
  // Source LINEAR (Cbf pre-swizzled in memory); LDS dest linear (= t*16
  // within the 4KB round -> wave-uniform base + lane*16 as required).
  const int srow = t >> 5;            // 0..7
  const int scol = (t & 31) * 16;     // 0..496
  const char* Bsrc = (const char*)Cbf + (size_t)srow * 512 + scol;

#define STAGE(CH, BUF)                                                        \
  {                                                                           \
    _Pragma("unroll")                                                         \
    for (int j = 0; j < 8; ++j)                                               \
      gload16(Bsrc + (size_t)(CH) * 32768 + j * 4096,                         \
              (char*)Bs[BUF] + j * 4096 + t * 16);                            \
  }

  // Issue chunk-0 staging first, then the A-loads (16 deep, independent).
  STAGE(0, 0)

  const char* Arow = (const char*)F + (size_t)(m0 + w * 16 + rl) * 1024 + kh * 32;
  f32x4 a0[8], a1[8];
#pragma unroll
  for (int kt = 0; kt < 8; ++kt) {
    a0[kt] = *reinterpret_cast<const f32x4*>(Arow + kt * 128);
    a1[kt] = *reinterpret_cast<const f32x4*>(Arow + kt * 128 + 16);
  }

  // Convert to bf16 fragments + exact fp32 row-norm partial (this lane's
  // 64 of the row's 256 elements).
  bf16x8 af[8];
  float rsq = 0.f;
#pragma unroll
  for (int kt = 0; kt < 8; ++kt) {
    const f32x4 x = a0[kt], y = a1[kt];
    rsq += x[0] * x[0] + x[1] * x[1] + x[2] * x[2] + x[3] * x[3] +
           y[0] * y[0] + y[1] * y[1] + y[2] * y[2] + y[3] * y[3];
    bf16x8 v;
    v[0] = (short)f2bf(x[0]); v[1] = (short)f2bf(x[1]);
    v[2] = (short)f2bf(x[2]); v[3] = (short)f2bf(x[3]);
    v[4] = (short)f2bf(y[0]); v[5] = (short)f2bf(y[1]);
    v[6] = (short)f2bf(y[2]); v[7] = (short)f2bf(y[3]);
    af[kt] = v;
  }
  // Sum the 4 kh-slices (lanes rl, rl+16, rl+32, rl+48) -> every lane holds
  // its F-row's full squared norm.
  float fv = rsq;
  fv += __shfl_xor(fv, 16);
  fv += __shfl_xor(fv, 32);

  // Chunk-0 staging guaranteed drained (A-loads issued after it; plus
  // explicit drain for safety against compiler reordering of issue order).
  asm volatile("s_waitcnt vmcnt(0)" ::: "memory");
  __builtin_amdgcn_s_barrier();
  asm volatile("" ::: "memory");

#pragma unroll
  for (int c = 0; c < NCH; ++c) {
    const int cur = c & 1;
    if (c < NCH - 1) {
      STAGE(c + 1, cur ^ 1)
      asm volatile("s_waitcnt vmcnt(8)" ::: "memory");   // chunk c landed; c+1 in flight
    } else {
      asm volatile("s_waitcnt vmcnt(0)" ::: "memory");
    }
    __builtin_amdgcn_s_barrier();    // all waves' chunk-c loads visible
    asm volatile("" ::: "memory");

    f32x4 acc[4];
#pragma unroll
    for (int ni = 0; ni < 4; ni++) acc[ni] = (f32x4){0.f, 0.f, 0.f, 0.f};

#pragma unroll
    for (int ni = 0; ni < 4; ni++) {
#pragma unroll
      for (int kt = 0; kt < 8; ++kt) {
        const bf16x8 bfr = *reinterpret_cast<const bf16x8*>(
            (const char*)Bs[cur] + (ni * 16 + rl) * 512 + ((kt * 64 + kh * 16) ^ amask));
        // SWAPPED operands: D row = center index, D col = F-row. [verified r7/r8]
        acc[ni] = __builtin_amdgcn_mfma_f32_16x16x32_bf16(bfr, af[kt], acc[ni], 0, 0, 0);
      }
    }

    // Emit this chunk's outputs: lane (rl,kh) reg r ->
    //   m = m0 + w*16 + rl,  n = c*64 + ni*16 + kh*4 + r  -> float4 stores.
#pragma unroll
    for (int ni = 0; ni < 4; ni++) {
      const int n = c * 64 + ni * 16 + kh * 4;
      const float4 cs4 = *reinterpret_cast<const float4*>(&csq[n]);
      float4 v;
      v.x = fv + cs4.x - 2.0f * acc[ni][0];
      v.y = fv + cs4.y - 2.0f * acc[ni][1];
      v.z = fv + cs4.z - 2.0f * acc[ni][2];
      v.w = fv + cs4.w - 2.0f * acc[ni][3];
      *reinterpret_cast<float4*>(&out[(size_t)(m0 + w * 16 + rl) * N + n]) = v;
    }

    __builtin_amdgcn_s_barrier();    // all reads of Bs[cur] done before restage
    asm volatile("" ::: "memory");
  }
}

extern "C" void kernel_launch(void* const* d_in, const int* in_sizes, int n_in,
                              void* d_out, int out_size, void* d_ws, size_t ws_size,
                              hipStream_t stream) {
  const float* F = (const float*)d_in[0];   // (16, 2048, 256) fp32
  const float* C = (const float*)d_in[1];   // (1, 512, 256) fp32
  float* out = (float*)d_out;               // (16, 2048, 512) fp32
  const int D = 256;
  const int M = in_sizes[0] / D;            // 32768
  const int N = in_sizes[1] / D;            // 512

  unsigned short* Cbf = (unsigned short*)d_ws;    // N*256 bf16 (128B-block swizzled)
  float* csq = (float*)(Cbf + (size_t)N * D);     // N fp32

  hipLaunchKernelGGL(prep_c, dim3(N / 4), dim3(256), 0, stream, C, Cbf, csq, N);
  hipLaunchKernelGGL(dist_fused, dim3(M / 64), dim3(256), 0, stream,
                     F, Cbf, csq, out, M, N);
}